// Round 10
// baseline (340.662 us; speedup 1.0000x reference)
//
#include <hip/hip_runtime.h>
#include <math.h>

#define N_TOK 2048
#define DIM   1024
#define BATCH 4

typedef float v4f  __attribute__((ext_vector_type(4)));
typedef __bf16 v8bf __attribute__((ext_vector_type(8)));
typedef unsigned short v8us __attribute__((ext_vector_type(8)));

static __device__ __forceinline__ unsigned short f2bf(float f) {
  unsigned int u = __float_as_uint(f);
  u += 0x7fffu + ((u >> 16) & 1u);          // round-to-nearest-even
  return (unsigned short)(u >> 16);
}
static __device__ __forceinline__ float bf2f(unsigned short h) {
  return __uint_as_float((unsigned int)h << 16);
}

// ------- merged: {hs cast + qp proj + r_embed} U {4x weight casts} ---------
__global__ __launch_bounds__(256) void prep_kernel(
    const float* __restrict__ hs, const float* __restrict__ Wtq,
    const float* __restrict__ btq, unsigned short* __restrict__ hs_b,
    float2* __restrict__ qp, float2* __restrict__ remb,
    const float* __restrict__ W0, const float* __restrict__ W1,
    const float* __restrict__ W2, const float* __restrict__ W3,
    unsigned short* __restrict__ D0, unsigned short* __restrict__ D1,
    unsigned short* __restrict__ D2, unsigned short* __restrict__ D3) {
  int bx = blockIdx.x;
  if (bx < 2048) {
    int w = threadIdx.x >> 6, lane = threadIdx.x & 63;
    int row = bx * 4 + w;
    const float* x = hs + (size_t)row * DIM;
    unsigned short* d = hs_b + (size_t)row * DIM;
    float a0 = 0.f, a1 = 0.f;
#pragma unroll
    for (int it = 0; it < 4; ++it) {
      int base = it * 256 + lane * 4;
      float4 v = *(const float4*)(x + base);
      float4 w0 = *(const float4*)(Wtq + base);
      float4 w1 = *(const float4*)(Wtq + DIM + base);
      ushort4 pk;
      pk.x = f2bf(v.x); pk.y = f2bf(v.y); pk.z = f2bf(v.z); pk.w = f2bf(v.w);
      *(ushort4*)(d + base) = pk;
      a0 += v.x * w0.x + v.y * w0.y + v.z * w0.z + v.w * w0.w;
      a1 += v.x * w1.x + v.y * w1.y + v.z * w1.z + v.w * w1.w;
    }
    for (int o = 32; o; o >>= 1) { a0 += __shfl_xor(a0, o); a1 += __shfl_xor(a1, o); }
    if (lane == 0) {
      a0 += btq[0]; a1 += btq[1];
      qp[row] = make_float2(a0, a1);
      float nrm = fmaxf(sqrtf(a0 * a0 + a1 * a1), 1e-12f);
      remb[row] = make_float2(a0 / nrm, a1 / nrm);
    }
  } else {
    int idx = bx - 2048;                 // 0..4095
    int mat = idx >> 10, blk = idx & 1023;
    const float* s;
    unsigned short* d;
    switch (mat) {
      case 0: s = W0; d = D0; break;
      case 1: s = W1; d = D1; break;
      case 2: s = W2; d = D2; break;
      default: s = W3; d = D3; break;
    }
    int i = (blk * 256 + threadIdx.x) * 4;
    float4 v = *(const float4*)(s + i);
    d[i + 0] = f2bf(v.x); d[i + 1] = f2bf(v.y);
    d[i + 2] = f2bf(v.z); d[i + 3] = f2bf(v.w);
  }
}

// ---- pairwise dist_sq moments: two-stage, NO atomics ----------------------
__global__ __launch_bounds__(256) void moments_kernel(
    const float2* __restrict__ qp, double* __restrict__ part) {
  int b = blockIdx.y;
  int i0 = blockIdx.x * 32;
  const float2* qb = qp + ((size_t)b << 11);
  double s1 = 0.0, s2 = 0.0;
  for (int idx = threadIdx.x; idx < 32 * N_TOK; idx += 256) {
    int i = i0 + (idx >> 11), j = idx & (N_TOK - 1);
    float2 pi = qb[i], pj = qb[j];
    float dx = pi.x - pj.x, dy = pi.y - pj.y;
    float dd = __fadd_rn(__fmul_rn(dx, dx), __fmul_rn(dy, dy)); // match ref (no fma)
    s1 += (double)dd;
    s2 += (double)dd * (double)dd;
  }
  int lane = threadIdx.x & 63, w = threadIdx.x >> 6;
  for (int o = 32; o; o >>= 1) { s1 += __shfl_xor(s1, o); s2 += __shfl_xor(s2, o); }
  __shared__ double red[8];
  if (lane == 0) { red[w] = s1; red[4 + w] = s2; }
  __syncthreads();
  if (threadIdx.x == 0) {
    int slot = b * 64 + blockIdx.x;
    part[slot * 2 + 0] = red[0] + red[1] + red[2] + red[3];
    part[slot * 2 + 1] = red[4] + red[5] + red[6] + red[7];
  }
}

__global__ __launch_bounds__(256) void thr_kernel(
    const double* __restrict__ part, float* __restrict__ thr) {
  int b = threadIdx.x >> 6, lane = threadIdx.x & 63;
  double s1 = part[(b * 64 + lane) * 2 + 0];
  double s2 = part[(b * 64 + lane) * 2 + 1];
  for (int o = 32; o; o >>= 1) { s1 += __shfl_xor(s1, o); s2 += __shfl_xor(s2, o); }
  if (lane == 0) {
    double n2 = (double)N_TOK * (double)N_TOK;
    double mean = s1 / n2;
    double var = (s2 - n2 * mean * mean) / (n2 - 1.0); // ddof=1
    if (var < 0.0) var = 0.0;
    thr[b] = (float)(mean + 1.25 * sqrt(var));
  }
}

// ============ 128xN tile K-loop (BK=64), XOR-swizzled LDS, drain ===========
// QKV only (NFRAG=4): 1536 blocks -> 4 resident/CU, TLP hides the drain.
template<int NFRAG>
__device__ __forceinline__ void gemm_ktile_loopN(
    const unsigned short* __restrict__ Ag, const unsigned short* __restrict__ Bg,
    int ldA, int ldB, int kEnd,
    unsigned short* As, unsigned short* Bs, v4f acc[4][NFRAG]) {
  const int tid  = threadIdx.x;
  const int lane = tid & 63;
  const int wm   = ((tid >> 6) & 1) << 6;
  const int wn   = (tid >> 7) * (NFRAG * 16);
  const int quad = lane >> 4, l16 = lane & 15;
  const int srow = tid >> 3;
  const int scol = ((tid ^ srow) & 7) * 8;   // XOR-swizzled global granule
  for (int k0 = 0; k0 < kEnd; k0 += 64) {
    __syncthreads();
#pragma unroll
    for (int it = 0; it < 4; ++it) {         // A: 128 rows
      const unsigned short* ga = Ag + (size_t)(srow + it * 32) * ldA + k0 + scol;
      unsigned short* la = As + (size_t)(it * 256 + (tid & ~63)) * 8;
      __builtin_amdgcn_global_load_lds((const __attribute__((address_space(1))) void*)ga,
                                       (__attribute__((address_space(3))) void*)la, 16, 0, 0);
    }
#pragma unroll
    for (int it = 0; it < NFRAG; ++it) {     // B: NFRAG*32 rows
      const unsigned short* gb = Bg + (size_t)(srow + it * 32) * ldB + k0 + scol;
      unsigned short* lb = Bs + (size_t)(it * 256 + (tid & ~63)) * 8;
      __builtin_amdgcn_global_load_lds((const __attribute__((address_space(1))) void*)gb,
                                       (__attribute__((address_space(3))) void*)lb, 16, 0, 0);
    }
    asm volatile("s_waitcnt vmcnt(0)" ::: "memory");
    __syncthreads();
#pragma unroll
    for (int kk = 0; kk < 64; kk += 32) {
      const int co = ((((kk >> 3) + quad) ^ (l16 & 7)) << 3);
      v8bf af[4], bfv[NFRAG];
#pragma unroll
      for (int i = 0; i < 4; ++i)
        af[i] = *(const v8bf*)(As + (wm + i * 16 + l16) * 64 + co);
#pragma unroll
      for (int i = 0; i < NFRAG; ++i)
        bfv[i] = *(const v8bf*)(Bs + (wn + i * 16 + l16) * 64 + co);
#pragma unroll
      for (int mi = 0; mi < 4; ++mi)
#pragma unroll
        for (int ni = 0; ni < NFRAG; ++ni)
          acc[mi][ni] = __builtin_amdgcn_mfma_f32_16x16x32_bf16(af[mi], bfv[ni], acc[mi][ni], 0, 0, 0);
    }
  }
}

// ============ counted-vmcnt dbuf 128x64 loop (tail GEMMs) ==================
// Never drains to 0 in steady state: each half-step waits only its own
// buffer's 6 loads via vmcnt(6) + raw s_barrier (no hardware drain).
// + T5 setprio around MFMA cluster (r9: tail net -5.5us incl. prep merge).
#define SBAR asm volatile("s_barrier" ::: "memory")

__device__ __forceinline__ void compute_12864(
    const unsigned short* As, const unsigned short* Bs,
    int wm, int wn, int quad, int l16, v4f acc[4][2]) {
#pragma unroll
  for (int kk = 0; kk < 64; kk += 32) {
    const int co = ((((kk >> 3) + quad) ^ (l16 & 7)) << 3);
    v8bf af[4], bfv[2];
#pragma unroll
    for (int i = 0; i < 4; ++i)
      af[i] = *(const v8bf*)(As + (wm + i * 16 + l16) * 64 + co);
#pragma unroll
    for (int i = 0; i < 2; ++i)
      bfv[i] = *(const v8bf*)(Bs + (wn + i * 16 + l16) * 64 + co);
    __builtin_amdgcn_s_setprio(1);
#pragma unroll
    for (int mi = 0; mi < 4; ++mi)
#pragma unroll
      for (int ni = 0; ni < 2; ++ni)
        acc[mi][ni] = __builtin_amdgcn_mfma_f32_16x16x32_bf16(af[mi], bfv[ni], acc[mi][ni], 0, 0, 0);
    __builtin_amdgcn_s_setprio(0);
  }
}

__device__ __forceinline__ void gemm_ktile_loop64_cnt(
    const unsigned short* __restrict__ Ag, const unsigned short* __restrict__ Bg,
    int ldA, int ldB, int kEnd,
    unsigned short* As0, unsigned short* Bs0,
    unsigned short* As1, unsigned short* Bs1, v4f acc[4][2]) {
  const int tid  = threadIdx.x;
  const int lane = tid & 63;
  const int wm   = ((tid >> 6) & 1) << 6;
  const int wn   = (tid >> 7) << 5;
  const int quad = lane >> 4, l16 = lane & 15;
  const int srow = tid >> 3;
  const int scol = ((tid ^ srow) & 7) * 8;   // XOR-swizzled global granule
  const unsigned short* gA = Ag + (size_t)srow * ldA + scol;
  const unsigned short* gB = Bg + (size_t)srow * ldB + scol;
  const int lbase = (tid & ~63) * 8;

  auto stage = [&](unsigned short* As, unsigned short* Bs, int k0) {
#pragma unroll
    for (int it = 0; it < 4; ++it) {         // A: 128 rows -> 4 loads/thread
      const unsigned short* ga = gA + (size_t)(it * 32) * ldA + k0;
      __builtin_amdgcn_global_load_lds((const __attribute__((address_space(1))) void*)ga,
                                       (__attribute__((address_space(3))) void*)(As + it * 2048 + lbase), 16, 0, 0);
    }
#pragma unroll
    for (int it = 0; it < 2; ++it) {         // B: 64 rows -> 2 loads/thread
      const unsigned short* gb = gB + (size_t)(it * 32) * ldB + k0;
      __builtin_amdgcn_global_load_lds((const __attribute__((address_space(1))) void*)gb,
                                       (__attribute__((address_space(3))) void*)(Bs + it * 2048 + lbase), 16, 0, 0);
    }
  };

  // prologue: both buffers in flight (12 outstanding/thread)
  stage(As0, Bs0, 0);
  stage(As1, Bs1, 64);
  int k0 = 0;
  for (; k0 + 128 < kEnd; k0 += 128) {
    asm volatile("s_waitcnt vmcnt(6)" ::: "memory");  // own buf0 landed
    SBAR;
    compute_12864(As0, Bs0, wm, wn, quad, l16, acc);
    SBAR;                                             // all done reading buf0
    stage(As0, Bs0, k0 + 128);
    asm volatile("s_waitcnt vmcnt(6)" ::: "memory");  // own buf1 landed
    SBAR;
    compute_12864(As1, Bs1, wm, wn, quad, l16, acc);
    SBAR;
    stage(As1, Bs1, k0 + 192);
  }
  asm volatile("s_waitcnt vmcnt(6)" ::: "memory");
  SBAR;
  compute_12864(As0, Bs0, wm, wn, quad, l16, acc);
  SBAR;
  asm volatile("s_waitcnt vmcnt(0)" ::: "memory");
  SBAR;
  compute_12864(As1, Bs1, wm, wn, quad, l16, acc);
}

#define PROLOG128                                                     \
  __shared__ __attribute__((aligned(16))) unsigned short smem[2][128 * 64];\
  unsigned short* As = smem[0];                                       \
  unsigned short* Bs = smem[1];                                       \
  v4f acc[4][4];                                                      \
  _Pragma("unroll") for (int i_ = 0; i_ < 4; ++i_)                    \
  _Pragma("unroll") for (int j_ = 0; j_ < 4; ++j_)                    \
      acc[i_][j_] = v4f{0.f, 0.f, 0.f, 0.f};                          \
  const int lane = threadIdx.x & 63, w = threadIdx.x >> 6;            \
  const int wm = (w & 1) << 6, wn = (w >> 1) << 6;                    \
  const int quad = lane >> 4, l16 = lane & 15;

#define PROLOG12864DB                                                 \
  __shared__ __attribute__((aligned(16))) unsigned short Asm[2][128 * 64];\
  __shared__ __attribute__((aligned(16))) unsigned short Bsm[2][64 * 64]; \
  v4f acc[4][2];                                                      \
  _Pragma("unroll") for (int i_ = 0; i_ < 4; ++i_)                    \
  _Pragma("unroll") for (int j_ = 0; j_ < 2; ++j_)                    \
      acc[i_][j_] = v4f{0.f, 0.f, 0.f, 0.f};                          \
  const int lane = threadIdx.x & 63, w = threadIdx.x >> 6;            \
  const int wm = (w & 1) << 6, wn = (w >> 1) << 5;                    \
  const int quad = lane >> 4, l16 = lane & 15;

// ------- fused QKV: X[8192,1024] @ Wqkv[3072,1024]^T -----------------------
// XCD-slab swizzle (VERIFIED: FETCH 77->49MB). LDS back to 32KB (r9's
// stride-136 pad regressed QKV 77->84); transpose conflict fixed instead by
// bijective XOR swizzle on the scratch T: token t of feature f lives at
// f*128 + (t ^ ((f&7)<<3)). Write: trow mult-of-4, s on bits 3-5 -> no
// carry, 16 lanes spread over 8 bank-pairs (2-way, free per m136). Read:
// aligned 8-token group stays contiguous at e0^s -> v8us read unchanged.
// Same involution both sides -> bit-identical data, zero extra LDS.
__global__ __launch_bounds__(256) void gemm_qkv_fused_kernel(
    const unsigned short* __restrict__ X, const unsigned short* __restrict__ Wqkv,
    const float* __restrict__ bq, const float* __restrict__ bk,
    const float* __restrict__ bv, unsigned short* __restrict__ q_b,
    unsigned short* __restrict__ k_b, unsigned short* __restrict__ v_t) {
  PROLOG128
  int lid = blockIdx.y * 24 + blockIdx.x;
  int xcd = lid & 7, slot = lid >> 3;
  int by = (xcd << 3) | (slot & 7);   // 0..63
  int bx = slot >> 3;                 // 0..23
  int m0 = by * 128, n0 = bx * 128;
  gemm_ktile_loopN<4>(X + (size_t)m0 * DIM, Wqkv + (size_t)n0 * DIM, DIM, DIM, DIM, As, Bs, acc);
  int region = n0 >> 10;  // 0:q 1:k 2:v (block-uniform)
  const float* bias = region == 0 ? bq : region == 1 ? bk : bv;
  int cbase = n0 & 1023;
  if (region < 2) {
    unsigned short* dst = region == 0 ? q_b : k_b;
#pragma unroll
    for (int mi = 0; mi < 4; ++mi) {
      int row0 = m0 + wm + mi * 16 + quad * 4;
#pragma unroll
      for (int ni = 0; ni < 4; ++ni) {
        int col = cbase + wn + ni * 16 + l16;
        float bcol = bias[col];
#pragma unroll
        for (int r = 0; r < 4; ++r)
          dst[(size_t)(row0 + r) * DIM + col] = f2bf(acc[mi][ni][r] + bcol);
      }
    }
  } else {
    // transpose tile through LDS (XOR-swizzled), then coalesced stores
    unsigned short* T = &smem[0][0];
    __syncthreads();
#pragma unroll
    for (int mi = 0; mi < 4; ++mi) {
      int trow = wm + mi * 16 + quad * 4;
#pragma unroll
      for (int ni = 0; ni < 4; ++ni) {
        int fcol = wn + ni * 16 + l16;
        float bcol = bias[cbase + fcol];
        ushort4 pk;
        pk.x = f2bf(acc[mi][ni][0] + bcol);
        pk.y = f2bf(acc[mi][ni][1] + bcol);
        pk.z = f2bf(acc[mi][ni][2] + bcol);
        pk.w = f2bf(acc[mi][ni][3] + bcol);
        *(ushort4*)(T + fcol * 128 + (trow ^ ((fcol & 7) << 3))) = pk;
      }
    }
    __syncthreads();
    int bb = m0 >> 11, tok0 = m0 & (N_TOK - 1);
    unsigned short* dstb = v_t + ((size_t)(bb << 10) + cbase) * N_TOK + tok0;
#pragma unroll
    for (int kk2 = 0; kk2 < 8; ++kk2) {
      int c = kk2 * 256 + threadIdx.x;
      int f = c >> 4, e0 = (c & 15) * 8;
      v8us v = *(const v8us*)(T + f * 128 + (e0 ^ ((f & 7) << 3)));
      *(v8us*)(dstb + (size_t)f * N_TOK + e0) = v;
    }
  }
}

// ------- scores: 128x64 trapezoid tiles (272/batch = 8 XCD x 34) -----------
__global__ __launch_bounds__(256) void gemm_scores_kernel(
    const unsigned short* __restrict__ q, const unsigned short* __restrict__ k,
    const float2* __restrict__ qp, const float* __restrict__ thr,
    unsigned short* __restrict__ S) {
  PROLOG12864DB
  int b = blockIdx.y;
  int lid = blockIdx.x;                 // 0..271
  int t = (lid & 7) * 34 + (lid >> 3);  // 272 = 8 XCDs x 34 contiguous tiles
  // ti(ti+1) <= t < (ti+1)(ti+2), tj in [0, 2ti+2)
  int ti = (int)((sqrtf(4.f * (float)t + 1.f) - 1.f) * 0.5f);
  while ((ti + 1) * (ti + 2) <= t) ++ti;
  while (ti * (ti + 1) > t) --ti;
  int tj = t - ti * (ti + 1);
  int i0 = ti * 128, j0 = tj * 64;
  const unsigned short* qb = q + (size_t)b * N_TOK * DIM;
  const unsigned short* kb = k + (size_t)b * N_TOK * DIM;
  gemm_ktile_loop64_cnt(qb + (size_t)i0 * DIM, kb + (size_t)j0 * DIM, DIM, DIM, DIM,
                        Asm[0], Bsm[0], Asm[1], Bsm[1], acc);
  float th = thr[b];
  const float2* qpb = qp + ((size_t)b << 11);
  unsigned short* Sb = S + (size_t)b * N_TOK * N_TOK;
  float2 pjv[2];
#pragma unroll
  for (int ni = 0; ni < 2; ++ni) pjv[ni] = qpb[j0 + wn + ni * 16 + l16];
#pragma unroll
  for (int mi = 0; mi < 4; ++mi) {
#pragma unroll
    for (int r = 0; r < 4; ++r) {
      int i = i0 + wm + mi * 16 + quad * 4 + r;
      float2 pi2 = qpb[i];
#pragma unroll
      for (int ni = 0; ni < 2; ++ni) {
        int j = j0 + wn + ni * 16 + l16;
        if (j <= i) {
          float dx = pi2.x - pjv[ni].x, dy = pi2.y - pjv[ni].y;
          float dd = __fadd_rn(__fmul_rn(dx, dx), __fmul_rn(dy, dy));
          bool ok = (dd <= th);
          // forward_bias==0 only when cos(atan2) rounds to -1 (dx<0, |dy| tiny)
          if (ok && dx < 0.f && fabsf(dy) <= 3e-4f * (-dx)) {
            float fb = 0.5f * (1.f + cosf(atan2f(dy, dx)));
            if (fb == 0.f) ok = false;
          }
          Sb[(size_t)i * N_TOK + j] = ok ? f2bf(acc[mi][ni][r] * 0.03125f) : 0xFF80; // -inf bf16
        }
      }
    }
  }
}

// ------- row softmax: S bf16 (j<=i) -> P bf16, zero-fill to 128-boundary ---
__global__ __launch_bounds__(256) void softmax_kernel(
    const unsigned short* __restrict__ S, unsigned short* __restrict__ P) {
  int row = blockIdx.x;
  int b = row >> 11, i = row & (N_TOK - 1);
  const unsigned short* s = S + ((size_t)b * N_TOK + i) * N_TOK;
  unsigned short* p = P + ((size_t)b * N_TOK + i) * N_TOK;
  int tid = threadIdx.x, lane = tid & 63, w = tid >> 6;
  int lim = i + 1;
  int tail0 = lim & ~7, ntail = lim - tail0;
  __shared__ float redmax[4], redsum[4];
  float mx = -__builtin_inff();
  for (int j = tid * 8; j + 8 <= lim; j += 2048) {
    v8us v = *(const v8us*)(s + j);
#pragma unroll
    for (int e = 0; e < 8; ++e) mx = fmaxf(mx, bf2f(v[e]));
  }
  if (tid < ntail) mx = fmaxf(mx, bf2f(s[tail0 + tid]));
  for (int o = 32; o; o >>= 1) mx = fmaxf(mx, __shfl_xor(mx, o));
  if (lane == 0) redmax[w] = mx;
  __syncthreads();
  mx = fmaxf(fmaxf(redmax[0], redmax[1]), fmaxf(redmax[2], redmax[3]));
  float sum = 0.f;
  for (int j = tid * 8; j + 8 <= lim; j += 2048) {
    v8us v = *(const v8us*)(s + j);
#pragma unroll
    for (int e = 0; e < 8; ++e) sum += __expf(bf2f(v[e]) - mx);
  }
  if (tid < ntail) sum += __expf(bf2f(s[tail0 + tid]) - mx);
  for (int o = 32; o; o >>= 1) sum += __shfl_xor(sum, o);
  if (lane == 0) redsum[w] = sum;
  __syncthreads();
  sum = redsum[0] + redsum[1] + redsum[2] + redsum[3];
  float inv = 1.f / sum;
  for (int j = tid * 8; j + 8 <= lim; j += 2048) {
    v8us v = *(const v8us*)(s + j);
    v8us o;
#pragma unroll
    for (int e = 0; e < 8; ++e) o[e] = f2bf(__expf(bf2f(v[e]) - mx) * inv);
    *(v8us*)(p + j) = o;
  }
  if (tid < ntail) p[tail0 + tid] = f2bf(__expf(bf2f(s[tail0 + tid]) - mx) * inv);
  int zs = (lim + 7) & ~7;
  if (tid < zs - lim) p[lim + tid] = 0;
  int rend = (lim + 127) & ~127;   // PV reads stop here for this row's tile
  v8us zv;
#pragma unroll
  for (int e = 0; e < 8; ++e) zv[e] = 0;
  for (int j = zs + tid * 8; j < rend; j += 2048) *(v8us*)(p + j) = zv;
}

// ------- context = P @ v (v transposed), 128x64 tiles, triangular K -------
__global__ __launch_bounds__(256) void gemm_pv_kernel(
    const unsigned short* __restrict__ P, const unsigned short* __restrict__ vt,
    unsigned short* __restrict__ ctx) {
  PROLOG12864DB
  int b = blockIdx.z;
  int ti = 15 - blockIdx.y;            // heavy blocks first
  int d0 = blockIdx.x * 64;
  int i0 = ti * 128;
  const unsigned short* Pb = P + (size_t)b * N_TOK * N_TOK;
  const unsigned short* Vb = vt + ((size_t)b * DIM + d0) * N_TOK;
  int kEnd = (ti + 1) * 128;
  gemm_ktile_loop64_cnt(Pb + (size_t)i0 * N_TOK, Vb, N_TOK, N_TOK, kEnd,
                        Asm[0], Bsm[0], Asm[1], Bsm[1], acc);
#pragma unroll
  for (int mi = 0; mi < 4; ++mi) {
    int row0 = i0 + wm + mi * 16 + quad * 4;
#pragma unroll
    for (int ni = 0; ni < 2; ++ni) {
      int d = d0 + wn + ni * 16 + l16;
#pragma unroll
      for (int r = 0; r < 4; ++r)
        ctx[((size_t)b * N_TOK + row0 + r) * DIM + d] = f2bf(acc[mi][ni][r]);
    }
  }
}

// ------- out = hs + ctx@Wo^T + bo + 0.1*(r_embed@Wfq^T + bfq), 128x64 -----
__global__ __launch_bounds__(256) void gemm_out_kernel(
    const unsigned short* __restrict__ ctx, const unsigned short* __restrict__ Wob,
    const float* __restrict__ bo, const float* __restrict__ hs,
    const float2* __restrict__ remb, const float* __restrict__ Wfq,
    const float* __restrict__ bfq, float* __restrict__ out) {
  PROLOG12864DB
  int lid = blockIdx.y * 16 + blockIdx.x;
  int xcd = lid & 7, slot = lid >> 3;   // slot 0..127
  int by = (xcd << 3) | (slot & 7);     // 0..63
  int bx = slot >> 3;                   // 0..15
  int m0 = by * 128, n0 = bx * 64;
  gemm_ktile_loop64_cnt(ctx + (size_t)m0 * DIM, Wob + (size_t)n0 * DIM, DIM, DIM, DIM,
                        Asm[0], Bsm[0], Asm[1], Bsm[1], acc);
#pragma unroll
  for (int mi = 0; mi < 4; ++mi) {
    int row0 = m0 + wm + mi * 16 + quad * 4;
#pragma unroll
    for (int ni = 0; ni < 2; ++ni) {
      int col = n0 + wn + ni * 16 + l16;
      float bias2 = bo[col] + 0.1f * bfq[col];
      float wf0 = 0.1f * Wfq[col * 2 + 0], wf1 = 0.1f * Wfq[col * 2 + 1];
#pragma unroll
      for (int r = 0; r < 4; ++r) {
        int row = row0 + r;
        float2 re = remb[row];
        out[(size_t)row * DIM + col] =
            acc[mi][ni][r] + bias2 + hs[(size_t)row * DIM + col] + re.x * wf0 + re.y * wf1;
      }
    }
  }
}

extern "C" void kernel_launch(void* const* d_in, const int* in_sizes, int n_in,
                              void* d_out, int out_size, void* d_ws, size_t ws_size,
                              hipStream_t stream) {
  const float* hs  = (const float*)d_in[0];
  const float* Wq  = (const float*)d_in[1];
  const float* bq  = (const float*)d_in[2];
  const float* Wk  = (const float*)d_in[3];
  const float* bk  = (const float*)d_in[4];
  const float* Wv  = (const float*)d_in[5];
  const float* bv  = (const float*)d_in[6];
  const float* Wo  = (const float*)d_in[7];
  const float* bo  = (const float*)d_in[8];
  const float* Wtq = (const float*)d_in[9];
  const float* btq = (const float*)d_in[10];
  const float* Wfq = (const float*)d_in[11];
  const float* bfq = (const float*)d_in[12];
  float* out = (float*)d_out;

  char* ws = (char*)d_ws;
  size_t off = 0;
  auto alloc = [&](size_t bytes) {
    char* p = ws + off;
    off += (bytes + 255) & ~(size_t)255;
    return p;
  };
  unsigned short* hs_b = (unsigned short*)alloc((size_t)8192 * 1024 * 2);  // 16.8MB
  unsigned short* q_b  = (unsigned short*)alloc((size_t)8192 * 1024 * 2);
  unsigned short* k_b  = (unsigned short*)alloc((size_t)8192 * 1024 * 2);  // contiguous after q_b (P alias)
  unsigned short* v_t  = (unsigned short*)alloc((size_t)8192 * 1024 * 2);
  // Wq_b/Wk_b/Wv_b MUST stay contiguous: fused QKV uses them as one [3072,1024].
  unsigned short* Wq_b = (unsigned short*)alloc((size_t)1024 * 1024 * 2);
  unsigned short* Wk_b = (unsigned short*)alloc((size_t)1024 * 1024 * 2);
  unsigned short* Wv_b = (unsigned short*)alloc((size_t)1024 * 1024 * 2);
  unsigned short* Wo_b = (unsigned short*)alloc((size_t)1024 * 1024 * 2);
  float2* qp   = (float2*)alloc((size_t)8192 * 8);
  float2* remb = (float2*)alloc((size_t)8192 * 8);
  double* part = (double*)alloc((size_t)BATCH * 64 * 2 * 8);
  float*  thr  = (float*)alloc(64);
  unsigned short* S = (unsigned short*)alloc((size_t)BATCH * N_TOK * N_TOK * 2);  // 33.6MB bf16
  // Aliases (lifetimes disjoint): P over q_b+k_b (33.6MB, both dead after
  // scores), ctx over hs_b (dead after QKV).
  unsigned short* P   = q_b;
  unsigned short* ctx = hs_b;

  prep_kernel<<<6144, 256, 0, stream>>>(hs, Wtq, btq, hs_b, qp, remb,
                                        Wq, Wk, Wv, Wo, Wq_b, Wk_b, Wv_b, Wo_b);
  moments_kernel<<<dim3(64, BATCH), 256, 0, stream>>>((const float2*)qp, part);
  thr_kernel<<<1, 256, 0, stream>>>(part, thr);

  gemm_qkv_fused_kernel<<<dim3(24, 64), 256, 0, stream>>>(
      hs_b, Wq_b, bq, bk, bv, q_b, k_b, v_t);

  gemm_scores_kernel<<<dim3(272, 4), 256, 0, stream>>>(
      q_b, k_b, (const float2*)qp, thr, S);

  softmax_kernel<<<8192, 256, 0, stream>>>(S, P);

  gemm_pv_kernel<<<dim3(16, 16, 4), 256, 0, stream>>>(P, v_t, ctx);

  gemm_out_kernel<<<dim3(16, 64), 256, 0, stream>>>(ctx, Wo_b, bo, hs, remb, Wfq, bfq, out);
}

// Round 11
// 330.067 us; speedup vs baseline: 1.0321x; 1.0321x over previous
//
#include <hip/hip_runtime.h>
#include <math.h>

#define N_TOK 2048
#define DIM   1024
#define BATCH 4

typedef float v4f  __attribute__((ext_vector_type(4)));
typedef __bf16 v8bf __attribute__((ext_vector_type(8)));
typedef unsigned short v8us __attribute__((ext_vector_type(8)));

static __device__ __forceinline__ unsigned short f2bf(float f) {
  unsigned int u = __float_as_uint(f);
  u += 0x7fffu + ((u >> 16) & 1u);          // round-to-nearest-even
  return (unsigned short)(u >> 16);
}
static __device__ __forceinline__ float bf2f(unsigned short h) {
  return __uint_as_float((unsigned int)h << 16);
}

// ------- merged: {hs cast + qp proj + r_embed} U {4x weight casts} ---------
__global__ __launch_bounds__(256) void prep_kernel(
    const float* __restrict__ hs, const float* __restrict__ Wtq,
    const float* __restrict__ btq, unsigned short* __restrict__ hs_b,
    float2* __restrict__ qp, float2* __restrict__ remb,
    const float* __restrict__ W0, const float* __restrict__ W1,
    const float* __restrict__ W2, const float* __restrict__ W3,
    unsigned short* __restrict__ D0, unsigned short* __restrict__ D1,
    unsigned short* __restrict__ D2, unsigned short* __restrict__ D3) {
  int bx = blockIdx.x;
  if (bx < 2048) {
    int w = threadIdx.x >> 6, lane = threadIdx.x & 63;
    int row = bx * 4 + w;
    const float* x = hs + (size_t)row * DIM;
    unsigned short* d = hs_b + (size_t)row * DIM;
    float a0 = 0.f, a1 = 0.f;
#pragma unroll
    for (int it = 0; it < 4; ++it) {
      int base = it * 256 + lane * 4;
      float4 v = *(const float4*)(x + base);
      float4 w0 = *(const float4*)(Wtq + base);
      float4 w1 = *(const float4*)(Wtq + DIM + base);
      ushort4 pk;
      pk.x = f2bf(v.x); pk.y = f2bf(v.y); pk.z = f2bf(v.z); pk.w = f2bf(v.w);
      *(ushort4*)(d + base) = pk;
      a0 += v.x * w0.x + v.y * w0.y + v.z * w0.z + v.w * w0.w;
      a1 += v.x * w1.x + v.y * w1.y + v.z * w1.z + v.w * w1.w;
    }
    for (int o = 32; o; o >>= 1) { a0 += __shfl_xor(a0, o); a1 += __shfl_xor(a1, o); }
    if (lane == 0) {
      a0 += btq[0]; a1 += btq[1];
      qp[row] = make_float2(a0, a1);
      float nrm = fmaxf(sqrtf(a0 * a0 + a1 * a1), 1e-12f);
      remb[row] = make_float2(a0 / nrm, a1 / nrm);
    }
  } else {
    int idx = bx - 2048;                 // 0..4095
    int mat = idx >> 10, blk = idx & 1023;
    const float* s;
    unsigned short* d;
    switch (mat) {
      case 0: s = W0; d = D0; break;
      case 1: s = W1; d = D1; break;
      case 2: s = W2; d = D2; break;
      default: s = W3; d = D3; break;
    }
    int i = (blk * 256 + threadIdx.x) * 4;
    float4 v = *(const float4*)(s + i);
    d[i + 0] = f2bf(v.x); d[i + 1] = f2bf(v.y);
    d[i + 2] = f2bf(v.z); d[i + 3] = f2bf(v.w);
  }
}

// ---- pairwise dist_sq moments: two-stage, NO atomics ----------------------
__global__ __launch_bounds__(256) void moments_kernel(
    const float2* __restrict__ qp, double* __restrict__ part) {
  int b = blockIdx.y;
  int i0 = blockIdx.x * 32;
  const float2* qb = qp + ((size_t)b << 11);
  double s1 = 0.0, s2 = 0.0;
  for (int idx = threadIdx.x; idx < 32 * N_TOK; idx += 256) {
    int i = i0 + (idx >> 11), j = idx & (N_TOK - 1);
    float2 pi = qb[i], pj = qb[j];
    float dx = pi.x - pj.x, dy = pi.y - pj.y;
    float dd = __fadd_rn(__fmul_rn(dx, dx), __fmul_rn(dy, dy)); // match ref (no fma)
    s1 += (double)dd;
    s2 += (double)dd * (double)dd;
  }
  int lane = threadIdx.x & 63, w = threadIdx.x >> 6;
  for (int o = 32; o; o >>= 1) { s1 += __shfl_xor(s1, o); s2 += __shfl_xor(s2, o); }
  __shared__ double red[8];
  if (lane == 0) { red[w] = s1; red[4 + w] = s2; }
  __syncthreads();
  if (threadIdx.x == 0) {
    int slot = b * 64 + blockIdx.x;
    part[slot * 2 + 0] = red[0] + red[1] + red[2] + red[3];
    part[slot * 2 + 1] = red[4] + red[5] + red[6] + red[7];
  }
}

__global__ __launch_bounds__(256) void thr_kernel(
    const double* __restrict__ part, float* __restrict__ thr) {
  int b = threadIdx.x >> 6, lane = threadIdx.x & 63;
  double s1 = part[(b * 64 + lane) * 2 + 0];
  double s2 = part[(b * 64 + lane) * 2 + 1];
  for (int o = 32; o; o >>= 1) { s1 += __shfl_xor(s1, o); s2 += __shfl_xor(s2, o); }
  if (lane == 0) {
    double n2 = (double)N_TOK * (double)N_TOK;
    double mean = s1 / n2;
    double var = (s2 - n2 * mean * mean) / (n2 - 1.0); // ddof=1
    if (var < 0.0) var = 0.0;
    thr[b] = (float)(mean + 1.25 * sqrt(var));
  }
}

// ============ 128xN tile K-loop (BK=64), XOR-swizzled LDS, drain ===========
// QKV only (NFRAG=4): 1536 blocks -> 4 resident/CU, TLP hides the drain.
template<int NFRAG>
__device__ __forceinline__ void gemm_ktile_loopN(
    const unsigned short* __restrict__ Ag, const unsigned short* __restrict__ Bg,
    int ldA, int ldB, int kEnd,
    unsigned short* As, unsigned short* Bs, v4f acc[4][NFRAG]) {
  const int tid  = threadIdx.x;
  const int lane = tid & 63;
  const int wm   = ((tid >> 6) & 1) << 6;
  const int wn   = (tid >> 7) * (NFRAG * 16);
  const int quad = lane >> 4, l16 = lane & 15;
  const int srow = tid >> 3;
  const int scol = ((tid ^ srow) & 7) * 8;   // XOR-swizzled global granule
  for (int k0 = 0; k0 < kEnd; k0 += 64) {
    __syncthreads();
#pragma unroll
    for (int it = 0; it < 4; ++it) {         // A: 128 rows
      const unsigned short* ga = Ag + (size_t)(srow + it * 32) * ldA + k0 + scol;
      unsigned short* la = As + (size_t)(it * 256 + (tid & ~63)) * 8;
      __builtin_amdgcn_global_load_lds((const __attribute__((address_space(1))) void*)ga,
                                       (__attribute__((address_space(3))) void*)la, 16, 0, 0);
    }
#pragma unroll
    for (int it = 0; it < NFRAG; ++it) {     // B: NFRAG*32 rows
      const unsigned short* gb = Bg + (size_t)(srow + it * 32) * ldB + k0 + scol;
      unsigned short* lb = Bs + (size_t)(it * 256 + (tid & ~63)) * 8;
      __builtin_amdgcn_global_load_lds((const __attribute__((address_space(1))) void*)gb,
                                       (__attribute__((address_space(3))) void*)lb, 16, 0, 0);
    }
    asm volatile("s_waitcnt vmcnt(0)" ::: "memory");
    __syncthreads();
#pragma unroll
    for (int kk = 0; kk < 64; kk += 32) {
      const int co = ((((kk >> 3) + quad) ^ (l16 & 7)) << 3);
      v8bf af[4], bfv[NFRAG];
#pragma unroll
      for (int i = 0; i < 4; ++i)
        af[i] = *(const v8bf*)(As + (wm + i * 16 + l16) * 64 + co);
#pragma unroll
      for (int i = 0; i < NFRAG; ++i)
        bfv[i] = *(const v8bf*)(Bs + (wn + i * 16 + l16) * 64 + co);
#pragma unroll
      for (int mi = 0; mi < 4; ++mi)
#pragma unroll
        for (int ni = 0; ni < NFRAG; ++ni)
          acc[mi][ni] = __builtin_amdgcn_mfma_f32_16x16x32_bf16(af[mi], bfv[ni], acc[mi][ni], 0, 0, 0);
    }
  }
}

// ============ counted-vmcnt dbuf loops =====================================
// Never drain to 0 in steady state: each half-step waits only its own
// buffer's loads via counted vmcnt + raw s_barrier (no hardware drain).
#define SBAR asm volatile("s_barrier" ::: "memory")

// ---- 256-thread 128x64 variant (scores; proven r8-r10) --------------------
__device__ __forceinline__ void compute_12864(
    const unsigned short* As, const unsigned short* Bs,
    int wm, int wn, int quad, int l16, v4f acc[4][2]) {
#pragma unroll
  for (int kk = 0; kk < 64; kk += 32) {
    const int co = ((((kk >> 3) + quad) ^ (l16 & 7)) << 3);
    v8bf af[4], bfv[2];
#pragma unroll
    for (int i = 0; i < 4; ++i)
      af[i] = *(const v8bf*)(As + (wm + i * 16 + l16) * 64 + co);
#pragma unroll
    for (int i = 0; i < 2; ++i)
      bfv[i] = *(const v8bf*)(Bs + (wn + i * 16 + l16) * 64 + co);
    __builtin_amdgcn_s_setprio(1);
#pragma unroll
    for (int mi = 0; mi < 4; ++mi)
#pragma unroll
      for (int ni = 0; ni < 2; ++ni)
        acc[mi][ni] = __builtin_amdgcn_mfma_f32_16x16x32_bf16(af[mi], bfv[ni], acc[mi][ni], 0, 0, 0);
    __builtin_amdgcn_s_setprio(0);
  }
}

__device__ __forceinline__ void gemm_ktile_loop64_cnt(
    const unsigned short* __restrict__ Ag, const unsigned short* __restrict__ Bg,
    int ldA, int ldB, int kEnd,
    unsigned short* As0, unsigned short* Bs0,
    unsigned short* As1, unsigned short* Bs1, v4f acc[4][2]) {
  const int tid  = threadIdx.x;
  const int lane = tid & 63;
  const int wm   = ((tid >> 6) & 1) << 6;
  const int wn   = (tid >> 7) << 5;
  const int quad = lane >> 4, l16 = lane & 15;
  const int srow = tid >> 3;
  const int scol = ((tid ^ srow) & 7) * 8;   // XOR-swizzled global granule
  const unsigned short* gA = Ag + (size_t)srow * ldA + scol;
  const unsigned short* gB = Bg + (size_t)srow * ldB + scol;
  const int lbase = (tid & ~63) * 8;

  auto stage = [&](unsigned short* As, unsigned short* Bs, int k0) {
#pragma unroll
    for (int it = 0; it < 4; ++it) {         // A: 128 rows -> 4 loads/thread
      const unsigned short* ga = gA + (size_t)(it * 32) * ldA + k0;
      __builtin_amdgcn_global_load_lds((const __attribute__((address_space(1))) void*)ga,
                                       (__attribute__((address_space(3))) void*)(As + it * 2048 + lbase), 16, 0, 0);
    }
#pragma unroll
    for (int it = 0; it < 2; ++it) {         // B: 64 rows -> 2 loads/thread
      const unsigned short* gb = gB + (size_t)(it * 32) * ldB + k0;
      __builtin_amdgcn_global_load_lds((const __attribute__((address_space(1))) void*)gb,
                                       (__attribute__((address_space(3))) void*)(Bs + it * 2048 + lbase), 16, 0, 0);
    }
  };

  stage(As0, Bs0, 0);
  stage(As1, Bs1, 64);
  int k0 = 0;
  for (; k0 + 128 < kEnd; k0 += 128) {
    asm volatile("s_waitcnt vmcnt(6)" ::: "memory");  // own buf0 landed
    SBAR;
    compute_12864(As0, Bs0, wm, wn, quad, l16, acc);
    SBAR;
    stage(As0, Bs0, k0 + 128);
    asm volatile("s_waitcnt vmcnt(6)" ::: "memory");  // own buf1 landed
    SBAR;
    compute_12864(As1, Bs1, wm, wn, quad, l16, acc);
    SBAR;
    stage(As1, Bs1, k0 + 192);
  }
  asm volatile("s_waitcnt vmcnt(6)" ::: "memory");
  SBAR;
  compute_12864(As0, Bs0, wm, wn, quad, l16, acc);
  SBAR;
  asm volatile("s_waitcnt vmcnt(0)" ::: "memory");
  SBAR;
  compute_12864(As1, Bs1, wm, wn, quad, l16, acc);
}

// ---- 512-thread 128x128 variant (PV/out this round) -----------------------
// Same counted skeleton widened to 8 waves (2M x 4N, wave tile 64x32):
// 64KB static LDS (proven size), 4 loads/thread/buffer -> vmcnt(4),
// 2 resident blocks/CU (16 waves/CU vs tail's 12), 1.5x FLOP per staged byte.
__device__ __forceinline__ void compute_128128w(
    const unsigned short* As, const unsigned short* Bs,
    int wm, int wn, int quad, int l16, v4f acc[4][2]) {
#pragma unroll
  for (int kk = 0; kk < 64; kk += 32) {
    const int co = ((((kk >> 3) + quad) ^ (l16 & 7)) << 3);
    v8bf af[4], bfv[2];
#pragma unroll
    for (int i = 0; i < 4; ++i)
      af[i] = *(const v8bf*)(As + (wm + i * 16 + l16) * 64 + co);
#pragma unroll
    for (int i = 0; i < 2; ++i)
      bfv[i] = *(const v8bf*)(Bs + (wn + i * 16 + l16) * 64 + co);
    __builtin_amdgcn_s_setprio(1);
#pragma unroll
    for (int mi = 0; mi < 4; ++mi)
#pragma unroll
      for (int ni = 0; ni < 2; ++ni)
        acc[mi][ni] = __builtin_amdgcn_mfma_f32_16x16x32_bf16(af[mi], bfv[ni], acc[mi][ni], 0, 0, 0);
    __builtin_amdgcn_s_setprio(0);
  }
}

__device__ __forceinline__ void gemm_ktile_loop128w_cnt(
    const unsigned short* __restrict__ Ag, const unsigned short* __restrict__ Bg,
    int ldA, int ldB, int kEnd,
    unsigned short* As0, unsigned short* Bs0,
    unsigned short* As1, unsigned short* Bs1, v4f acc[4][2],
    int wm, int wn, int quad, int l16) {
  const int tid  = threadIdx.x;              // 0..511
  const int srow = tid >> 3;                 // 0..63
  const int scol = ((tid ^ srow) & 7) * 8;   // XOR-swizzled global granule
  const unsigned short* gA = Ag + (size_t)srow * ldA + scol;
  const unsigned short* gB = Bg + (size_t)srow * ldB + scol;
  const int lbase = (tid & ~63) * 8;         // wave w -> rows 8w..8w+7 of pass

  auto stage = [&](unsigned short* As, unsigned short* Bs, int k0) {
#pragma unroll
    for (int it = 0; it < 2; ++it) {         // A: 128 rows -> 2x64-row passes
      const unsigned short* ga = gA + (size_t)(it * 64) * ldA + k0;
      __builtin_amdgcn_global_load_lds((const __attribute__((address_space(1))) void*)ga,
                                       (__attribute__((address_space(3))) void*)(As + it * 4096 + lbase), 16, 0, 0);
    }
#pragma unroll
    for (int it = 0; it < 2; ++it) {         // B: 128 rows -> 2x64-row passes
      const unsigned short* gb = gB + (size_t)(it * 64) * ldB + k0;
      __builtin_amdgcn_global_load_lds((const __attribute__((address_space(1))) void*)gb,
                                       (__attribute__((address_space(3))) void*)(Bs + it * 4096 + lbase), 16, 0, 0);
    }
  };

  stage(As0, Bs0, 0);
  stage(As1, Bs1, 64);
  int k0 = 0;
  for (; k0 + 128 < kEnd; k0 += 128) {
    asm volatile("s_waitcnt vmcnt(4)" ::: "memory");  // own buf0 landed
    SBAR;
    compute_128128w(As0, Bs0, wm, wn, quad, l16, acc);
    SBAR;
    stage(As0, Bs0, k0 + 128);
    asm volatile("s_waitcnt vmcnt(4)" ::: "memory");  // own buf1 landed
    SBAR;
    compute_128128w(As1, Bs1, wm, wn, quad, l16, acc);
    SBAR;
    stage(As1, Bs1, k0 + 192);
  }
  asm volatile("s_waitcnt vmcnt(4)" ::: "memory");
  SBAR;
  compute_128128w(As0, Bs0, wm, wn, quad, l16, acc);
  SBAR;
  asm volatile("s_waitcnt vmcnt(0)" ::: "memory");
  SBAR;
  compute_128128w(As1, Bs1, wm, wn, quad, l16, acc);
}

#define PROLOG128                                                     \
  __shared__ __attribute__((aligned(16))) unsigned short smem[2][128 * 64];\
  unsigned short* As = smem[0];                                       \
  unsigned short* Bs = smem[1];                                       \
  v4f acc[4][4];                                                      \
  _Pragma("unroll") for (int i_ = 0; i_ < 4; ++i_)                    \
  _Pragma("unroll") for (int j_ = 0; j_ < 4; ++j_)                    \
      acc[i_][j_] = v4f{0.f, 0.f, 0.f, 0.f};                          \
  const int lane = threadIdx.x & 63, w = threadIdx.x >> 6;            \
  const int wm = (w & 1) << 6, wn = (w >> 1) << 6;                    \
  const int quad = lane >> 4, l16 = lane & 15;

#define PROLOG12864DB                                                 \
  __shared__ __attribute__((aligned(16))) unsigned short Asm[2][128 * 64];\
  __shared__ __attribute__((aligned(16))) unsigned short Bsm[2][64 * 64]; \
  v4f acc[4][2];                                                      \
  _Pragma("unroll") for (int i_ = 0; i_ < 4; ++i_)                    \
  _Pragma("unroll") for (int j_ = 0; j_ < 2; ++j_)                    \
      acc[i_][j_] = v4f{0.f, 0.f, 0.f, 0.f};                          \
  const int lane = threadIdx.x & 63, w = threadIdx.x >> 6;            \
  const int wm = (w & 1) << 6, wn = (w >> 1) << 5;                    \
  const int quad = lane >> 4, l16 = lane & 15;

// 512-thread prolog: 8 waves as 2M x 4N; wave tile 64 rows x 32 cols.
#define PROLOG128128W                                                 \
  __shared__ __attribute__((aligned(16))) unsigned short Asm[2][128 * 64];\
  __shared__ __attribute__((aligned(16))) unsigned short Bsm[2][128 * 64];\
  v4f acc[4][2];                                                      \
  _Pragma("unroll") for (int i_ = 0; i_ < 4; ++i_)                    \
  _Pragma("unroll") for (int j_ = 0; j_ < 2; ++j_)                    \
      acc[i_][j_] = v4f{0.f, 0.f, 0.f, 0.f};                          \
  const int lane = threadIdx.x & 63, wid = threadIdx.x >> 6;          \
  const int wm = (wid & 1) << 6, wn = (wid >> 1) << 5;                \
  const int quad = lane >> 4, l16 = lane & 15;

// ------- fused QKV: X[8192,1024] @ Wqkv[3072,1024]^T -----------------------
// XCD-slab swizzle (VERIFIED: FETCH 77->49MB). r10: 73.1us, conflicts 131K.
__global__ __launch_bounds__(256) void gemm_qkv_fused_kernel(
    const unsigned short* __restrict__ X, const unsigned short* __restrict__ Wqkv,
    const float* __restrict__ bq, const float* __restrict__ bk,
    const float* __restrict__ bv, unsigned short* __restrict__ q_b,
    unsigned short* __restrict__ k_b, unsigned short* __restrict__ v_t) {
  PROLOG128
  int lid = blockIdx.y * 24 + blockIdx.x;
  int xcd = lid & 7, slot = lid >> 3;
  int by = (xcd << 3) | (slot & 7);   // 0..63
  int bx = slot >> 3;                 // 0..23
  int m0 = by * 128, n0 = bx * 128;
  gemm_ktile_loopN<4>(X + (size_t)m0 * DIM, Wqkv + (size_t)n0 * DIM, DIM, DIM, DIM, As, Bs, acc);
  int region = n0 >> 10;  // 0:q 1:k 2:v (block-uniform)
  const float* bias = region == 0 ? bq : region == 1 ? bk : bv;
  int cbase = n0 & 1023;
  if (region < 2) {
    unsigned short* dst = region == 0 ? q_b : k_b;
#pragma unroll
    for (int mi = 0; mi < 4; ++mi) {
      int row0 = m0 + wm + mi * 16 + quad * 4;
#pragma unroll
      for (int ni = 0; ni < 4; ++ni) {
        int col = cbase + wn + ni * 16 + l16;
        float bcol = bias[col];
#pragma unroll
        for (int r = 0; r < 4; ++r)
          dst[(size_t)(row0 + r) * DIM + col] = f2bf(acc[mi][ni][r] + bcol);
      }
    }
  } else {
    // transpose tile through LDS (XOR-swizzled: bit-identical, 2-way banks)
    unsigned short* T = &smem[0][0];
    __syncthreads();
#pragma unroll
    for (int mi = 0; mi < 4; ++mi) {
      int trow = wm + mi * 16 + quad * 4;
#pragma unroll
      for (int ni = 0; ni < 4; ++ni) {
        int fcol = wn + ni * 16 + l16;
        float bcol = bias[cbase + fcol];
        ushort4 pk;
        pk.x = f2bf(acc[mi][ni][0] + bcol);
        pk.y = f2bf(acc[mi][ni][1] + bcol);
        pk.z = f2bf(acc[mi][ni][2] + bcol);
        pk.w = f2bf(acc[mi][ni][3] + bcol);
        *(ushort4*)(T + fcol * 128 + (trow ^ ((fcol & 7) << 3))) = pk;
      }
    }
    __syncthreads();
    int bb = m0 >> 11, tok0 = m0 & (N_TOK - 1);
    unsigned short* dstb = v_t + ((size_t)(bb << 10) + cbase) * N_TOK + tok0;
#pragma unroll
    for (int kk2 = 0; kk2 < 8; ++kk2) {
      int c = kk2 * 256 + threadIdx.x;
      int f = c >> 4, e0 = (c & 15) * 8;
      v8us v = *(const v8us*)(T + f * 128 + (e0 ^ ((f & 7) << 3)));
      *(v8us*)(dstb + (size_t)f * N_TOK + e0) = v;
    }
  }
}

// ------- scores: 128x64 trapezoid tiles (272/batch = 8 XCD x 34) -----------
__global__ __launch_bounds__(256) void gemm_scores_kernel(
    const unsigned short* __restrict__ q, const unsigned short* __restrict__ k,
    const float2* __restrict__ qp, const float* __restrict__ thr,
    unsigned short* __restrict__ S) {
  PROLOG12864DB
  int b = blockIdx.y;
  int lid = blockIdx.x;                 // 0..271
  int t = (lid & 7) * 34 + (lid >> 3);  // 272 = 8 XCDs x 34 contiguous tiles
  int ti = (int)((sqrtf(4.f * (float)t + 1.f) - 1.f) * 0.5f);
  while ((ti + 1) * (ti + 2) <= t) ++ti;
  while (ti * (ti + 1) > t) --ti;
  int tj = t - ti * (ti + 1);
  int i0 = ti * 128, j0 = tj * 64;
  const unsigned short* qb = q + (size_t)b * N_TOK * DIM;
  const unsigned short* kb = k + (size_t)b * N_TOK * DIM;
  gemm_ktile_loop64_cnt(qb + (size_t)i0 * DIM, kb + (size_t)j0 * DIM, DIM, DIM, DIM,
                        Asm[0], Bsm[0], Asm[1], Bsm[1], acc);
  float th = thr[b];
  const float2* qpb = qp + ((size_t)b << 11);
  unsigned short* Sb = S + (size_t)b * N_TOK * N_TOK;
  float2 pjv[2];
#pragma unroll
  for (int ni = 0; ni < 2; ++ni) pjv[ni] = qpb[j0 + wn + ni * 16 + l16];
#pragma unroll
  for (int mi = 0; mi < 4; ++mi) {
#pragma unroll
    for (int r = 0; r < 4; ++r) {
      int i = i0 + wm + mi * 16 + quad * 4 + r;
      float2 pi2 = qpb[i];
#pragma unroll
      for (int ni = 0; ni < 2; ++ni) {
        int j = j0 + wn + ni * 16 + l16;
        if (j <= i) {
          float dx = pi2.x - pjv[ni].x, dy = pi2.y - pjv[ni].y;
          float dd = __fadd_rn(__fmul_rn(dx, dx), __fmul_rn(dy, dy));
          bool ok = (dd <= th);
          // forward_bias==0 only when cos(atan2) rounds to -1 (dx<0, |dy| tiny)
          if (ok && dx < 0.f && fabsf(dy) <= 3e-4f * (-dx)) {
            float fb = 0.5f * (1.f + cosf(atan2f(dy, dx)));
            if (fb == 0.f) ok = false;
          }
          Sb[(size_t)i * N_TOK + j] = ok ? f2bf(acc[mi][ni][r] * 0.03125f) : 0xFF80; // -inf bf16
        }
      }
    }
  }
}

// ------- row softmax: S bf16 (j<=i) -> P bf16, zero-fill to 128-boundary ---
__global__ __launch_bounds__(256) void softmax_kernel(
    const unsigned short* __restrict__ S, unsigned short* __restrict__ P) {
  int row = blockIdx.x;
  int b = row >> 11, i = row & (N_TOK - 1);
  const unsigned short* s = S + ((size_t)b * N_TOK + i) * N_TOK;
  unsigned short* p = P + ((size_t)b * N_TOK + i) * N_TOK;
  int tid = threadIdx.x, lane = tid & 63, w = tid >> 6;
  int lim = i + 1;
  int tail0 = lim & ~7, ntail = lim - tail0;
  __shared__ float redmax[4], redsum[4];
  float mx = -__builtin_inff();
  for (int j = tid * 8; j + 8 <= lim; j += 2048) {
    v8us v = *(const v8us*)(s + j);
#pragma unroll
    for (int e = 0; e < 8; ++e) mx = fmaxf(mx, bf2f(v[e]));
  }
  if (tid < ntail) mx = fmaxf(mx, bf2f(s[tail0 + tid]));
  for (int o = 32; o; o >>= 1) mx = fmaxf(mx, __shfl_xor(mx, o));
  if (lane == 0) redmax[w] = mx;
  __syncthreads();
  mx = fmaxf(fmaxf(redmax[0], redmax[1]), fmaxf(redmax[2], redmax[3]));
  float sum = 0.f;
  for (int j = tid * 8; j + 8 <= lim; j += 2048) {
    v8us v = *(const v8us*)(s + j);
#pragma unroll
    for (int e = 0; e < 8; ++e) sum += __expf(bf2f(v[e]) - mx);
  }
  if (tid < ntail) sum += __expf(bf2f(s[tail0 + tid]) - mx);
  for (int o = 32; o; o >>= 1) sum += __shfl_xor(sum, o);
  if (lane == 0) redsum[w] = sum;
  __syncthreads();
  sum = redsum[0] + redsum[1] + redsum[2] + redsum[3];
  float inv = 1.f / sum;
  for (int j = tid * 8; j + 8 <= lim; j += 2048) {
    v8us v = *(const v8us*)(s + j);
    v8us o;
#pragma unroll
    for (int e = 0; e < 8; ++e) o[e] = f2bf(__expf(bf2f(v[e]) - mx) * inv);
    *(v8us*)(p + j) = o;
  }
  if (tid < ntail) p[tail0 + tid] = f2bf(__expf(bf2f(s[tail0 + tid]) - mx) * inv);
  int zs = (lim + 7) & ~7;
  if (tid < zs - lim) p[lim + tid] = 0;
  int rend = (lim + 127) & ~127;   // PV reads stop here (i-granularity 128)
  v8us zv;
#pragma unroll
  for (int e = 0; e < 8; ++e) zv[e] = 0;
  for (int j = zs + tid * 8; j < rend; j += 2048) *(v8us*)(p + j) = zv;
}

// ------- context = P @ v (v transposed), 128x128 tiles, 512thr, counted ---
// Grid (8,16,4)=512 blocks = exactly 2/CU. kEnd=(ti+1)*128, heavy-first.
__global__ __launch_bounds__(512, 4) void gemm_pv_kernel(
    const unsigned short* __restrict__ P, const unsigned short* __restrict__ vt,
    unsigned short* __restrict__ ctx) {
  PROLOG128128W
  int b = blockIdx.z;
  int ti = 15 - blockIdx.y;            // heavy blocks first
  int d0 = blockIdx.x * 128;
  int i0 = ti * 128;
  const unsigned short* Pb = P + (size_t)b * N_TOK * N_TOK;
  const unsigned short* Vb = vt + ((size_t)b * DIM + d0) * N_TOK;
  int kEnd = (ti + 1) * 128;
  gemm_ktile_loop128w_cnt(Pb + (size_t)i0 * N_TOK, Vb, N_TOK, N_TOK, kEnd,
                          Asm[0], Bsm[0], Asm[1], Bsm[1], acc, wm, wn, quad, l16);
#pragma unroll
  for (int mi = 0; mi < 4; ++mi) {
    int row0 = i0 + wm + mi * 16 + quad * 4;
#pragma unroll
    for (int ni = 0; ni < 2; ++ni) {
      int d = d0 + wn + ni * 16 + l16;
#pragma unroll
      for (int r = 0; r < 4; ++r)
        ctx[((size_t)b * N_TOK + row0 + r) * DIM + d] = f2bf(acc[mi][ni][r]);
    }
  }
}

// ------- out = hs + ctx@Wo^T + bo + 0.1*(r_embed@Wfq^T + bfq) --------------
// 128x128 tiles, 512thr counted; grid 512 = 2/CU with XCD slab swizzle.
__global__ __launch_bounds__(512, 4) void gemm_out_kernel(
    const unsigned short* __restrict__ ctx, const unsigned short* __restrict__ Wob,
    const float* __restrict__ bo, const float* __restrict__ hs,
    const float2* __restrict__ remb, const float* __restrict__ Wfq,
    const float* __restrict__ bfq, float* __restrict__ out) {
  PROLOG128128W
  int lid = blockIdx.y * 8 + blockIdx.x;
  int xcd = lid & 7, slot = lid >> 3;   // slot 0..63
  int by = (xcd << 3) | (slot & 7);     // 0..63
  int bx = slot >> 3;                   // 0..7
  int m0 = by * 128, n0 = bx * 128;
  gemm_ktile_loop128w_cnt(ctx + (size_t)m0 * DIM, Wob + (size_t)n0 * DIM, DIM, DIM, DIM,
                          Asm[0], Bsm[0], Asm[1], Bsm[1], acc, wm, wn, quad, l16);
#pragma unroll
  for (int mi = 0; mi < 4; ++mi) {
    int row0 = m0 + wm + mi * 16 + quad * 4;
#pragma unroll
    for (int ni = 0; ni < 2; ++ni) {
      int col = n0 + wn + ni * 16 + l16;
      float bias2 = bo[col] + 0.1f * bfq[col];
      float wf0 = 0.1f * Wfq[col * 2 + 0], wf1 = 0.1f * Wfq[col * 2 + 1];
#pragma unroll
      for (int r = 0; r < 4; ++r) {
        int row = row0 + r;
        float2 re = remb[row];
        out[(size_t)row * DIM + col] =
            acc[mi][ni][r] + bias2 + hs[(size_t)row * DIM + col] + re.x * wf0 + re.y * wf1;
      }
    }
  }
}

extern "C" void kernel_launch(void* const* d_in, const int* in_sizes, int n_in,
                              void* d_out, int out_size, void* d_ws, size_t ws_size,
                              hipStream_t stream) {
  const float* hs  = (const float*)d_in[0];
  const float* Wq  = (const float*)d_in[1];
  const float* bq  = (const float*)d_in[2];
  const float* Wk  = (const float*)d_in[3];
  const float* bk  = (const float*)d_in[4];
  const float* Wv  = (const float*)d_in[5];
  const float* bv  = (const float*)d_in[6];
  const float* Wo  = (const float*)d_in[7];
  const float* bo  = (const float*)d_in[8];
  const float* Wtq = (const float*)d_in[9];
  const float* btq = (const float*)d_in[10];
  const float* Wfq = (const float*)d_in[11];
  const float* bfq = (const float*)d_in[12];
  float* out = (float*)d_out;

  char* ws = (char*)d_ws;
  size_t off = 0;
  auto alloc = [&](size_t bytes) {
    char* p = ws + off;
    off += (bytes + 255) & ~(size_t)255;
    return p;
  };
  unsigned short* hs_b = (unsigned short*)alloc((size_t)8192 * 1024 * 2);  // 16.8MB
  unsigned short* q_b  = (unsigned short*)alloc((size_t)8192 * 1024 * 2);
  unsigned short* k_b  = (unsigned short*)alloc((size_t)8192 * 1024 * 2);  // contiguous after q_b (P alias)
  unsigned short* v_t  = (unsigned short*)alloc((size_t)8192 * 1024 * 2);
  // Wq_b/Wk_b/Wv_b MUST stay contiguous: fused QKV uses them as one [3072,1024].
  unsigned short* Wq_b = (unsigned short*)alloc((size_t)1024 * 1024 * 2);
  unsigned short* Wk_b = (unsigned short*)alloc((size_t)1024 * 1024 * 2);
  unsigned short* Wv_b = (unsigned short*)alloc((size_t)1024 * 1024 * 2);
  unsigned short* Wo_b = (unsigned short*)alloc((size_t)1024 * 1024 * 2);
  float2* qp   = (float2*)alloc((size_t)8192 * 8);
  float2* remb = (float2*)alloc((size_t)8192 * 8);
  double* part = (double*)alloc((size_t)BATCH * 64 * 2 * 8);
  float*  thr  = (float*)alloc(64);
  unsigned short* S = (unsigned short*)alloc((size_t)BATCH * N_TOK * N_TOK * 2);  // 33.6MB bf16
  // Aliases (lifetimes disjoint): P over q_b+k_b (33.6MB, both dead after
  // scores), ctx over hs_b (dead after QKV).
  unsigned short* P   = q_b;
  unsigned short* ctx = hs_b;

  prep_kernel<<<6144, 256, 0, stream>>>(hs, Wtq, btq, hs_b, qp, remb,
                                        Wq, Wk, Wv, Wo, Wq_b, Wk_b, Wv_b, Wo_b);
  moments_kernel<<<dim3(64, BATCH), 256, 0, stream>>>((const float2*)qp, part);
  thr_kernel<<<1, 256, 0, stream>>>(part, thr);

  gemm_qkv_fused_kernel<<<dim3(24, 64), 256, 0, stream>>>(
      hs_b, Wq_b, bq, bk, bv, q_b, k_b, v_t);

  gemm_scores_kernel<<<dim3(272, 4), 256, 0, stream>>>(
      q_b, k_b, (const float2*)qp, thr, S);

  softmax_kernel<<<8192, 256, 0, stream>>>(S, P);

  gemm_pv_kernel<<<dim3(8, 16, 4), 512, 0, stream>>>(P, v_t, ctx);

  gemm_out_kernel<<<dim3(8, 64), 512, 0, stream>>>(ctx, Wo_b, bo, hs, remb, Wfq, bfq, out);
}